// Round 1
// baseline (1791.880 us; speedup 1.0000x reference)
//
#include <hip/hip_runtime.h>
#include <hip/hip_bf16.h>
#include <stdint.h>

// Problem dims
#define BATCH 256
#define SEQ   512
#define INDIM 64
#define H     128
#define NG    512   // 4*H gates

using short8  = __attribute__((ext_vector_type(8))) short;  // 8 bf16 (4 VGPRs) MFMA A/B frag
using float4v = __attribute__((ext_vector_type(4))) float;  // MFMA C/D frag

__device__ __forceinline__ unsigned short f2bf(float f) {
    union { float f; uint32_t u; } v; v.f = f;
    uint32_t u = v.u;
    return (unsigned short)((u + 0x7FFFu + ((u >> 16) & 1u)) >> 16); // RNE
}

__device__ __forceinline__ float sigmoid_fast(float x) {
    float e = __expf(-x);
    return 1.f / (1.f + e);
}
__device__ __forceinline__ float tanh_fast(float x) {
    // 1 - 2/(1+e^{2x}); saturates correctly at +-inf via __expf over/underflow
    float e = __expf(2.f * x);
    return 1.f - 2.f / (e + 1.f);
}

// ---------------- x fp32 -> bf16 convert ----------------
__global__ void conv_x_kernel(const float* __restrict__ x,
                              unsigned short* __restrict__ xb, int n4) {
    int i = blockIdx.x * blockDim.x + threadIdx.x;
    if (i >= n4) return;
    float4 f = ((const float4*)x)[i];
    ushort4 o;
    o.x = f2bf(f.x); o.y = f2bf(f.y); o.z = f2bf(f.z); o.w = f2bf(f.w);
    ((ushort4*)xb)[i] = o;
}

// ---------------- persistent-weight LSTM layer ----------------
// 16 blocks x 512 threads (8 waves). Block owns batch rows [16*bid, 16*bid+16).
// Wave w owns cells [16w, 16w+16): one 16x16 n-tile per gate type {i,f,g,o},
// so gate quads align per-lane in C-layout -> in-register cell update.
// W_ih and W_hh fragments are converted fp32->bf16 in-kernel and stay in VGPRs
// across all 512 timesteps. h round-trips through LDS (double-buffered).
template<int KIN, bool WRITE_SEQ>
__global__ __launch_bounds__(512, 2)
void lstm_layer_kernel(const unsigned short* __restrict__ xin, // [BATCH][SEQ][KIN] bf16
                       const float* __restrict__ Wih,          // [NG][KIN] fp32
                       const float* __restrict__ Whh,          // [NG][H]  fp32
                       const float* __restrict__ b_ih,
                       const float* __restrict__ b_hh,
                       unsigned short* __restrict__ outseq,    // [BATCH][SEQ][H] bf16
                       float* __restrict__ outlast)            // [BATCH][H] fp32
{
    constexpr int KT = KIN / 32;           // k-tiles for input projection
    const int w    = threadIdx.x >> 6;     // wave 0..7
    const int lane = threadIdx.x & 63;
    const int quad = lane >> 4;
    const int l16  = lane & 15;
    const int b0   = blockIdx.x * 16;
    const int cell = w * 16 + l16;         // this lane's cell column (n within H)

    __shared__ short hbuf[2][16][136];     // h_{t-1} bf16, row-padded 128->136 (16B-aligned, bank-spread)

    for (int i = threadIdx.x; i < 2 * 16 * 136; i += blockDim.x)
        ((short*)hbuf)[i] = 0;

    // ---- load weight fragments (once), fp32 -> bf16 in registers ----
    // B-frag layout: lane holds B[k = quad*8+j][n = l16(+tile)], i.e. 8 consecutive k
    // of row n of the [N][K] weight matrix (m97 gemm_bt pattern).
    short8 whh_f[4][4];   // [gate type][k-tile]
    short8 wih_f[4][KT];
    float  bias[4];
#pragma unroll
    for (int tT = 0; tT < 4; tT++) {
        const int n = tT * 128 + cell;
#pragma unroll
        for (int kt = 0; kt < 4; kt++) {
            const float* p = Whh + (size_t)n * H + kt * 32 + quad * 8;
            float4 f0 = *(const float4*)p;
            float4 f1 = *(const float4*)(p + 4);
            short8 s;
            s[0]=f2bf(f0.x); s[1]=f2bf(f0.y); s[2]=f2bf(f0.z); s[3]=f2bf(f0.w);
            s[4]=f2bf(f1.x); s[5]=f2bf(f1.y); s[6]=f2bf(f1.z); s[7]=f2bf(f1.w);
            whh_f[tT][kt] = s;
        }
#pragma unroll
        for (int kt = 0; kt < KT; kt++) {
            const float* p = Wih + (size_t)n * KIN + kt * 32 + quad * 8;
            float4 f0 = *(const float4*)p;
            float4 f1 = *(const float4*)(p + 4);
            short8 s;
            s[0]=f2bf(f0.x); s[1]=f2bf(f0.y); s[2]=f2bf(f0.z); s[3]=f2bf(f0.w);
            s[4]=f2bf(f1.x); s[5]=f2bf(f1.y); s[6]=f2bf(f1.z); s[7]=f2bf(f1.w);
            wih_f[tT][kt] = s;
        }
        bias[tT] = b_ih[n] + b_hh[n];
    }

    float c[4] = {0.f, 0.f, 0.f, 0.f};     // c-state fp32, rows quad*4+r

    // x A-frags: lane holds A[m = l16][k = quad*8+j]; double-buffered prefetch
    short8 xf0[KT], xf1[KT];
    {
        const unsigned short* p = xin + ((size_t)(b0 + l16) * SEQ + 0) * KIN + quad * 8;
#pragma unroll
        for (int kt = 0; kt < KT; kt++) xf0[kt] = *(const short8*)(p + kt * 32);
    }
    __syncthreads();

    auto step = [&](int t, int cur, short8 (&xuse)[KT], short8 (&xpre)[KT]) {
        // prefetch x for t+1 (clamped; hidden behind this step's compute)
        {
            const int tn = (t + 1 < SEQ) ? t + 1 : SEQ - 1;
            const unsigned short* p = xin + ((size_t)(b0 + l16) * SEQ + tn) * KIN + quad * 8;
#pragma unroll
            for (int kt = 0; kt < KT; kt++) xpre[kt] = *(const short8*)(p + kt * 32);
        }
        // h_{t-1} A-frags from LDS
        short8 ha[4];
#pragma unroll
        for (int kt = 0; kt < 4; kt++)
            ha[kt] = *(const short8*)&hbuf[cur][l16][kt * 32 + quad * 8];

        // gates = b + x@Wih^T + h@Whh^T  (fp32 accum, bias pre-splatted)
        float4v acc[4];
#pragma unroll
        for (int tT = 0; tT < 4; tT++)
            acc[tT] = (float4v){bias[tT], bias[tT], bias[tT], bias[tT]};
#pragma unroll
        for (int tT = 0; tT < 4; tT++) {
#pragma unroll
            for (int kt = 0; kt < KT; kt++)
                acc[tT] = __builtin_amdgcn_mfma_f32_16x16x32_bf16(xuse[kt], wih_f[tT][kt], acc[tT], 0, 0, 0);
#pragma unroll
            for (int kt = 0; kt < 4; kt++)
                acc[tT] = __builtin_amdgcn_mfma_f32_16x16x32_bf16(ha[kt], whh_f[tT][kt], acc[tT], 0, 0, 0);
        }

        // cell update: C-layout row m = quad*4 + r, col = cell
#pragma unroll
        for (int r = 0; r < 4; r++) {
            float si = sigmoid_fast(acc[0][r]);
            float sf = sigmoid_fast(acc[1][r]);
            float tg = tanh_fast(acc[2][r]);
            float so = sigmoid_fast(acc[3][r]);
            float cn = sf * c[r] + si * tg;
            c[r] = cn;
            float h = so * tanh_fast(cn);
            const int m = quad * 4 + r;
            const unsigned short hb = f2bf(h);
            hbuf[cur ^ 1][m][cell] = (short)hb;
            if (WRITE_SEQ) {
                outseq[((size_t)(b0 + m) * SEQ + t) * H + cell] = hb;
            } else if (t == SEQ - 1) {
                outlast[(size_t)(b0 + m) * H + cell] = h;
            }
        }
        __syncthreads();   // next step reads hbuf[cur^1]; WAR on hbuf[cur] is safe (read before this barrier)
    };

    for (int t = 0; t < SEQ; t += 2) {
        step(t,     0, xf0, xf1);
        step(t + 1, 1, xf1, xf0);
    }
}

// ---------------- MLP head: relu(h@W1^T + b1)@W2^T + b2 ----------------
__global__ void head_kernel(const float* __restrict__ hlast,  // [BATCH][H]
                            const float* __restrict__ W1, const float* __restrict__ b1,
                            const float* __restrict__ W2, const float* __restrict__ b2,
                            float* __restrict__ out) {        // [BATCH][3]
    __shared__ float hrow[128];
    __shared__ float arow[64];
    const int b = blockIdx.x, tid = threadIdx.x;
    hrow[tid]      = hlast[(size_t)b * H + tid];
    hrow[tid + 64] = hlast[(size_t)b * H + 64 + tid];
    __syncthreads();
    float s = b1[tid];
#pragma unroll 8
    for (int k = 0; k < 128; k++) s += hrow[k] * W1[tid * 128 + k];
    arow[tid] = fmaxf(s, 0.f);
    __syncthreads();
    if (tid < 3) {
        float o = b2[tid];
#pragma unroll 8
        for (int j = 0; j < 64; j++) o += arow[j] * W2[tid * 64 + j];
        out[b * 3 + tid] = o;
    }
}

extern "C" void kernel_launch(void* const* d_in, const int* in_sizes, int n_in,
                              void* d_out, int out_size, void* d_ws, size_t ws_size,
                              hipStream_t stream) {
    const float* x     = (const float*)d_in[0];
    const float* W_ih0 = (const float*)d_in[1];
    const float* W_hh0 = (const float*)d_in[2];
    const float* b_ih0 = (const float*)d_in[3];
    const float* b_hh0 = (const float*)d_in[4];
    const float* W_ih1 = (const float*)d_in[5];
    const float* W_hh1 = (const float*)d_in[6];
    const float* b_ih1 = (const float*)d_in[7];
    const float* b_hh1 = (const float*)d_in[8];
    const float* W1    = (const float*)d_in[9];
    const float* b1    = (const float*)d_in[10];
    const float* W2    = (const float*)d_in[11];
    const float* b2    = (const float*)d_in[12];
    float* out = (float*)d_out;

    // workspace layout (bytes):
    //   xb    bf16[256*512*64]   @ 0          (16,777,216 B)
    //   h0sq  bf16[256*512*128]  @ 16777216   (33,554,432 B)
    //   hlast f32 [256*128]      @ 50331648   (131,072 B)   -> total ~50.5 MB
    char* ws = (char*)d_ws;
    unsigned short* xb    = (unsigned short*)ws;
    unsigned short* h0sq  = (unsigned short*)(ws + 16777216);
    float*          hlast = (float*)(ws + 16777216 + 33554432);

    conv_x_kernel<<<8192, 256, 0, stream>>>(x, xb, (BATCH * SEQ * INDIM) / 4);
    lstm_layer_kernel<64,  true ><<<16, 512, 0, stream>>>(xb,   W_ih0, W_hh0, b_ih0, b_hh0, h0sq, nullptr);
    lstm_layer_kernel<128, false><<<16, 512, 0, stream>>>(h0sq, W_ih1, W_hh1, b_ih1, b_hh1, nullptr, hlast);
    head_kernel<<<BATCH, 64, 0, stream>>>(hlast, W1, b1, W2, b2, out);
}

// Round 2
// 852.053 us; speedup vs baseline: 2.1030x; 2.1030x over previous
//
#include <hip/hip_runtime.h>
#include <hip/hip_bf16.h>
#include <stdint.h>

// Problem dims
#define BATCH 256
#define SEQ   512
#define INDIM 64
#define H     128
#define CH    16              // pipeline handoff chunk (steps)
#define NCH   (SEQ / CH)

using short8  = __attribute__((ext_vector_type(8))) short;  // 8 bf16 MFMA A/B frag
using float4v = __attribute__((ext_vector_type(4))) float;  // MFMA C/D frag

#define LOG2E 1.4426950408889634f

__device__ __forceinline__ unsigned short f2bf(float f) {
    union { float f; uint32_t u; } v; v.f = f;
    uint32_t u = v.u;
    return (unsigned short)((u + 0x7FFFu + ((u >> 16) & 1u)) >> 16); // RNE
}

__device__ __forceinline__ float fast_exp2(float x) {
#if __has_builtin(__builtin_amdgcn_exp2f)
    return __builtin_amdgcn_exp2f(x);      // raw v_exp_f32
#else
    return __expf(x * 0.6931471805599453f);
#endif
}
__device__ __forceinline__ float fast_rcp(float x) {
#if __has_builtin(__builtin_amdgcn_rcpf)
    return __builtin_amdgcn_rcpf(x);       // raw v_rcp_f32 (~1 ulp, no IEEE div sequence)
#else
    return 1.f / x;
#endif
}
__device__ __forceinline__ float sigmoid_fast(float x) {
    return fast_rcp(1.f + fast_exp2(-LOG2E * x));
}
__device__ __forceinline__ float tanh_fast(float x) {
    // 1 - 2/(1+2^(2x*log2e)); saturates correctly via exp over/underflow
    return fmaf(-2.f, fast_rcp(1.f + fast_exp2((2.f * LOG2E) * x)), 1.f);
}

// ---------------- x fp32 -> bf16 convert ----------------
__global__ void conv_x_kernel(const float* __restrict__ x,
                              unsigned short* __restrict__ xb, int n4) {
    int i = blockIdx.x * blockDim.x + threadIdx.x;
    if (i >= n4) return;
    float4 f = ((const float4*)x)[i];
    ushort4 o;
    o.x = f2bf(f.x); o.y = f2bf(f.y); o.z = f2bf(f.z); o.w = f2bf(f.w);
    ((ushort4*)xb)[i] = o;
}

__global__ void zero_flags_kernel(int* flags) {
    if (threadIdx.x < 16) flags[threadIdx.x] = 0;
}

// ---------------- fused 2-layer pipelined LSTM ----------------
// 32 blocks x 512 threads. Blocks 0..15: layer0 (producer), 16..31: layer1
// (consumer), paired 1:1 on batch-tile bt. Producer publishes h chunks of
// CH steps via release-scope atomic flag (agent scope -> L2 writeback);
// consumer acquire-spins (-> L2 invalidate) then proceeds.
// Per block: 16 batch rows; wave w owns cells [16w,16w+16) x 4 gate types,
// so all four gates of a cell land at the same (lane,reg) in C-layout ->
// pure per-lane cell update. Weights persist in VGPRs all 512 steps.
template<int KIN, bool IS_PROD>
__device__ __forceinline__ void lstm_body(
    const unsigned short* __restrict__ xin,  // [BATCH][SEQ][KIN] bf16
    const float* __restrict__ Wih,           // [4H][KIN]
    const float* __restrict__ Whh,           // [4H][H]
    const float* __restrict__ b_ih, const float* __restrict__ b_hh,
    unsigned short* __restrict__ outseq,     // producer: [BATCH][SEQ][H] bf16
    float* __restrict__ outlast,             // consumer: [BATCH][H] fp32
    int* flag, int bt)
{
    constexpr int KT  = KIN / 32;
    constexpr int PAD = 132;                 // 66 dwords == 2 mod 32 -> 2-way (free) bank aliasing
    const int w    = threadIdx.x >> 6;
    const int lane = threadIdx.x & 63;
    const int quad = lane >> 4;
    const int l16  = lane & 15;
    const int b0   = bt * 16;
    const int cell = w * 16 + l16;

    __shared__ short hbuf[2][16][PAD];
    for (int i = threadIdx.x; i < 2 * 16 * PAD; i += 512) ((short*)hbuf)[i] = 0;

    // ---- weight fragments (loaded once, fp32->bf16, stay in registers) ----
    short8 whh_f[4][4];
    short8 wih_f[4][KT];
    float  bias[4];
#pragma unroll
    for (int tT = 0; tT < 4; tT++) {
        const int n = tT * 128 + cell;
#pragma unroll
        for (int kt = 0; kt < 4; kt++) {
            const float* p = Whh + (size_t)n * H + kt * 32 + quad * 8;
            float4 f0 = *(const float4*)p;
            float4 f1 = *(const float4*)(p + 4);
            short8 s;
            s[0]=f2bf(f0.x); s[1]=f2bf(f0.y); s[2]=f2bf(f0.z); s[3]=f2bf(f0.w);
            s[4]=f2bf(f1.x); s[5]=f2bf(f1.y); s[6]=f2bf(f1.z); s[7]=f2bf(f1.w);
            whh_f[tT][kt] = s;
        }
#pragma unroll
        for (int kt = 0; kt < KT; kt++) {
            const float* p = Wih + (size_t)n * KIN + kt * 32 + quad * 8;
            float4 f0 = *(const float4*)p;
            float4 f1 = *(const float4*)(p + 4);
            short8 s;
            s[0]=f2bf(f0.x); s[1]=f2bf(f0.y); s[2]=f2bf(f0.z); s[3]=f2bf(f0.w);
            s[4]=f2bf(f1.x); s[5]=f2bf(f1.y); s[6]=f2bf(f1.z); s[7]=f2bf(f1.w);
            wih_f[tT][kt] = s;
        }
        bias[tT] = b_ih[n] + b_hh[n];
    }

    float c[4] = {0.f, 0.f, 0.f, 0.f};

    // hoisted per-lane pointers
    const unsigned short* xp = xin + ((size_t)(b0 + l16) * SEQ) * KIN + quad * 8;
    unsigned short* op[4];
    if (IS_PROD) {
#pragma unroll
        for (int r = 0; r < 4; r++)
            op[r] = outseq + ((size_t)(b0 + quad * 4 + r) * SEQ) * H + cell;
    }

    short8 xcur[KT], xnxt[KT];
    __syncthreads();   // hbuf zero-init visible

    auto step = [&](int t, int cur, short8 (&xuse)[KT], short8 (&xpre)[KT], bool do_pre) {
        if (do_pre) {
            const unsigned short* p = xp + (size_t)(t + 1) * KIN;
#pragma unroll
            for (int kt = 0; kt < KT; kt++) xpre[kt] = *(const short8*)(p + kt * 32);
        }
        short8 ha[4];
#pragma unroll
        for (int kt = 0; kt < 4; kt++)
            ha[kt] = *(const short8*)&hbuf[cur][l16][kt * 32 + quad * 8];

        float4v acc[4];
#pragma unroll
        for (int tT = 0; tT < 4; tT++)
            acc[tT] = (float4v){bias[tT], bias[tT], bias[tT], bias[tT]};
#pragma unroll
        for (int tT = 0; tT < 4; tT++) {
#pragma unroll
            for (int kt = 0; kt < KT; kt++)
                acc[tT] = __builtin_amdgcn_mfma_f32_16x16x32_bf16(xuse[kt], wih_f[tT][kt], acc[tT], 0, 0, 0);
#pragma unroll
            for (int kt = 0; kt < 4; kt++)
                acc[tT] = __builtin_amdgcn_mfma_f32_16x16x32_bf16(ha[kt], whh_f[tT][kt], acc[tT], 0, 0, 0);
        }

        // cell update: C-layout row m = quad*4 + r, col = cell
#pragma unroll
        for (int r = 0; r < 4; r++) {
            float si = sigmoid_fast(acc[0][r]);
            float sf = sigmoid_fast(acc[1][r]);
            float tg = tanh_fast(acc[2][r]);
            float so = sigmoid_fast(acc[3][r]);
            float cn = fmaf(sf, c[r], si * tg);
            c[r] = cn;
            float h = so * tanh_fast(cn);
            const unsigned short hb = f2bf(h);
            hbuf[cur ^ 1][quad * 4 + r][cell] = (short)hb;
            if (IS_PROD) {
                *op[r] = hb;
            } else if (t == SEQ - 1) {
                outlast[(size_t)(b0 + quad * 4 + r) * H + cell] = h;
            }
        }
        if (IS_PROD) {
#pragma unroll
            for (int r = 0; r < 4; r++) op[r] += H;
        }
        __syncthreads();   // next step reads hbuf[cur^1]
    };

    for (int ch = 0; ch < NCH; ch++) {
        const int t0 = ch * CH;
        if (!IS_PROD) {
            if (threadIdx.x == 0) {
                while (__hip_atomic_load(flag, __ATOMIC_ACQUIRE, __HIP_MEMORY_SCOPE_AGENT) <= ch) {
                    __builtin_amdgcn_s_sleep(2);
                }
            }
            __syncthreads();   // release all threads after data is visible (L2 invalidated by acquire)
        }
        // load x for first step of chunk
        {
            const unsigned short* p = xp + (size_t)t0 * KIN;
#pragma unroll
            for (int kt = 0; kt < KT; kt++) xcur[kt] = *(const short8*)(p + kt * 32);
        }
#pragma unroll 1
        for (int i = 0; i < CH; i += 2) {
            step(t0 + i,     0, xcur, xnxt, true);
            step(t0 + i + 1, 1, xnxt, xcur, (i + 2) < CH);
        }
        if (IS_PROD) {
            // all threads' chunk stores drained to L2 by the step barrier;
            // release-scope atomic writes back L2 then bumps the flag
            if (threadIdx.x == 0)
                __hip_atomic_fetch_add(flag, 1, __ATOMIC_RELEASE, __HIP_MEMORY_SCOPE_AGENT);
        }
    }
}

__global__ __launch_bounds__(512, 2)
void lstm_fused_kernel(const unsigned short* __restrict__ xb,
                       const float* __restrict__ Wih0, const float* __restrict__ Whh0,
                       const float* __restrict__ bih0, const float* __restrict__ bhh0,
                       const float* __restrict__ Wih1, const float* __restrict__ Whh1,
                       const float* __restrict__ bih1, const float* __restrict__ bhh1,
                       unsigned short* __restrict__ h0sq, float* __restrict__ hlast,
                       int* __restrict__ flags)
{
    const int bt = blockIdx.x & 15;
    if (blockIdx.x < 16)
        lstm_body<64,  true >(xb,   Wih0, Whh0, bih0, bhh0, h0sq, nullptr, flags + bt, bt);
    else
        lstm_body<128, false>(h0sq, Wih1, Whh1, bih1, bhh1, nullptr, hlast, flags + bt, bt);
}

// ---------------- MLP head ----------------
__global__ void head_kernel(const float* __restrict__ hlast,
                            const float* __restrict__ W1, const float* __restrict__ b1,
                            const float* __restrict__ W2, const float* __restrict__ b2,
                            float* __restrict__ out) {
    __shared__ float hrow[128];
    __shared__ float arow[64];
    const int b = blockIdx.x, tid = threadIdx.x;
    hrow[tid]      = hlast[(size_t)b * H + tid];
    hrow[tid + 64] = hlast[(size_t)b * H + 64 + tid];
    __syncthreads();
    float s = b1[tid];
#pragma unroll 8
    for (int k = 0; k < 128; k++) s += hrow[k] * W1[tid * 128 + k];
    arow[tid] = fmaxf(s, 0.f);
    __syncthreads();
    if (tid < 3) {
        float o = b2[tid];
#pragma unroll 8
        for (int j = 0; j < 64; j++) o += arow[j] * W2[tid * 64 + j];
        out[b * 3 + tid] = o;
    }
}

extern "C" void kernel_launch(void* const* d_in, const int* in_sizes, int n_in,
                              void* d_out, int out_size, void* d_ws, size_t ws_size,
                              hipStream_t stream) {
    const float* x     = (const float*)d_in[0];
    const float* W_ih0 = (const float*)d_in[1];
    const float* W_hh0 = (const float*)d_in[2];
    const float* b_ih0 = (const float*)d_in[3];
    const float* b_hh0 = (const float*)d_in[4];
    const float* W_ih1 = (const float*)d_in[5];
    const float* W_hh1 = (const float*)d_in[6];
    const float* b_ih1 = (const float*)d_in[7];
    const float* b_hh1 = (const float*)d_in[8];
    const float* W1    = (const float*)d_in[9];
    const float* b1    = (const float*)d_in[10];
    const float* W2    = (const float*)d_in[11];
    const float* b2    = (const float*)d_in[12];
    float* out = (float*)d_out;

    // workspace layout (bytes):
    //   xb    bf16[256*512*64]   @ 0          (16,777,216)
    //   h0sq  bf16[256*512*128]  @ 16777216   (33,554,432)
    //   hlast f32 [256*128]      @ 50331648   (131,072)
    //   flags int[16]            @ 50462720
    char* ws = (char*)d_ws;
    unsigned short* xb    = (unsigned short*)ws;
    unsigned short* h0sq  = (unsigned short*)(ws + 16777216);
    float*          hlast = (float*)(ws + 50331648);
    int*            flags = (int*)(ws + 50462720);

    zero_flags_kernel<<<1, 64, 0, stream>>>(flags);
    conv_x_kernel<<<8192, 256, 0, stream>>>(x, xb, (BATCH * SEQ * INDIM) / 4);
    lstm_fused_kernel<<<32, 512, 0, stream>>>(xb, W_ih0, W_hh0, b_ih0, b_hh0,
                                              W_ih1, W_hh1, b_ih1, b_hh1,
                                              h0sq, hlast, flags);
    head_kernel<<<BATCH, 64, 0, stream>>>(hlast, W1, b1, W2, b2, out);
}